// Round 7
// baseline (611.232 us; speedup 1.0000x reference)
//
#include <hip/hip_runtime.h>

#define DIM 1536
#define IMG 1024
#define TXT 256
#define SEQ 1280
#define NH 24
#define HD 64
#define SD ((size_t)SEQ * DIM)
#define IDSZ ((size_t)IMG * DIM)
#define WSZ ((size_t)DIM * DIM)
#define NTIL 12
#define KTIL 48
#define TILE_USH 4096   // 64 rows x 64 ushorts = 8KB B-tile image

typedef __attribute__((ext_vector_type(8))) short short8;
typedef __attribute__((ext_vector_type(4))) float f32x4;

__device__ __forceinline__ float bf2f(ushort u) {
    union { unsigned int i; float f; } v; v.i = ((unsigned int)u) << 16; return v.f;
}
__device__ __forceinline__ ushort f2bf(float f) {
    union { unsigned int i; float f; } v; v.f = f;
    unsigned int u = v.i;
    u += 0x7fffu + ((u >> 16) & 1u);
    return (ushort)(u >> 16);
}
// Truncating f32 -> bf16 for lo-residual planes only.
__device__ __forceinline__ ushort f2bf_rz(float f) {
    union { unsigned int i; float f; } v; v.f = f;
    return (ushort)(v.i >> 16);
}

// ---------------------------------------------------------------------------
// Input-dtype detector (flag=1 -> fp32 underneath, flag=0 -> bf16).
// ---------------------------------------------------------------------------
__global__ __launch_bounds__(256) void detect_dtype(const void* __restrict__ p,
                                                    int* __restrict__ flag)
{
    __shared__ int cnt;
    if (threadIdx.x == 0) cnt = 0;
    __syncthreads();
    const ushort* u = (const ushort*)p;
    int local = 0;
    for (int i = threadIdx.x; i < 2048; i += 256) {
        ushort v = u[2 * i];
        int e = (v >> 7) & 0xFF;
        if (e >= 0xC0) local++;
    }
    atomicAdd(&cnt, local);
    __syncthreads();
    if (threadIdx.x == 0) flag[0] = (cnt > 16) ? 1 : 0;
}

// ---------------------------------------------------------------------------
// One-time bf16 conversion of the 4 X inputs (flat layout).
// ---------------------------------------------------------------------------
struct CvtP {
    const void* src[4];
    ushort* dst[4];
    int n8[4];
};

__global__ __launch_bounds__(256) void convert_bf16(CvtP p, const int* __restrict__ dflag)
{
    const int a = blockIdx.y;
    const int i = blockIdx.x * 256 + threadIdx.x;
    if (i >= p.n8[a]) return;
    const size_t off = (size_t)i * 8;
    uint4 o;
    if (dflag[0]) {
        const float* s = (const float*)p.src[a] + off;
        const float4 f0 = *(const float4*)s;
        const float4 f1 = *(const float4*)(s + 4);
        ushort t[8];
        t[0] = f2bf(f0.x); t[1] = f2bf(f0.y); t[2] = f2bf(f0.z); t[3] = f2bf(f0.w);
        t[4] = f2bf(f1.x); t[5] = f2bf(f1.y); t[6] = f2bf(f1.z); t[7] = f2bf(f1.w);
        o = *(uint4*)t;
    } else {
        o = *(const uint4*)((const ushort*)p.src[a] + off);
    }
    *(uint4*)(p.dst[a] + off) = o;
}

// ---------------------------------------------------------------------------
// One-time weight -> LDS B-tile image. Image layout per (widx, nt, kt):
// 4096 ushorts = exact double of the GEMM Bs plane: u32 at ushort addr
// R*64 + gx*8 + bo holds (W[k0+bkk][n0+rr], W[k0+bkk+1][n0+rr]) with
// R=rr&63, half=rr>>6, gx=((half<<2)+bkg)^(R&7)^(R>>3).
// Staging in the GEMMs then becomes a pure contiguous copy.
// ---------------------------------------------------------------------------
struct WImgP {
    const void* src[16];   // 12 qkv + 4 out weights (original dtype)
    ushort* img;           // [16][NTIL][KTIL][TILE_USH]
};

__global__ __launch_bounds__(256) void convert_wimg(WImgP p, const int* __restrict__ dflag)
{
    const int widx = blockIdx.y;
    const int nt = blockIdx.x / KTIL, kt = blockIdx.x - nt * KTIL;
    const int t = threadIdx.x;
    const int bn8 = (t & 15) << 3, bkk = (t >> 4) << 1;
    const int bkg = bkk >> 3, bo = bkk & 7;
    const int k0 = kt * 32, n0 = nt * 128;

    ushort t0[8], t1[8];
    if (dflag[0]) {
        const float* w = (const float*)p.src[widx];
        const float* r0 = w + (size_t)(k0 + bkk) * DIM + n0 + bn8;
        float x0[8], x1[8];
        *(float4*)&x0[0] = *(const float4*)r0;
        *(float4*)&x0[4] = *(const float4*)(r0 + 4);
        *(float4*)&x1[0] = *(const float4*)(r0 + DIM);
        *(float4*)&x1[4] = *(const float4*)(r0 + DIM + 4);
#pragma unroll
        for (int j = 0; j < 8; ++j) { t0[j] = f2bf(x0[j]); t1[j] = f2bf(x1[j]); }
    } else {
        const ushort* w = (const ushort*)p.src[widx];
        const ushort* r0 = w + (size_t)(k0 + bkk) * DIM + n0 + bn8;
        *(uint4*)t0 = *(const uint4*)r0;
        *(uint4*)t1 = *(const uint4*)(r0 + DIM);
    }

    ushort* img = p.img + (((size_t)widx * NTIL + nt) * KTIL + kt) * TILE_USH;
#pragma unroll
    for (int j = 0; j < 8; ++j) {
        const int rr = bn8 + j;
        const int R = rr & 63, half = rr >> 6;
        const int gx = (((half << 2) + bkg) ^ (R & 7) ^ (R >> 3)) & 7;
        *(unsigned int*)&img[R * 64 + gx * 8 + bo] =
            (unsigned int)t0[j] | ((unsigned int)t1[j] << 16);
    }
}

#define LSTR 40

// ===========================================================================
// Merged QKV GEMM over bf16 X and pre-imaged weights. grid (36, 20).
// B staging = contiguous copy of the 8KB tile image (no pack VALU).
// ===========================================================================
struct QKV3P {
    const ushort* Xb;     // [2][SEQ][DIM] bf16
    const ushort* Wimg;   // [16][NTIL][KTIL][TILE_USH]
    const void* B[12];
    float* Y[6];
    ushort* Yh[6];
    ushort* Yl[6];
};

__global__ __launch_bounds__(256) void gemm_qkv_v5(QKV3P p, const int* __restrict__ dflag)
{
    __shared__ __align__(16) ushort As[2][128 * LSTR];
    __shared__ __align__(16) ushort Bs[2][64 * 64];
    const int dt = dflag[0];
    const int bx = blockIdx.x;
    const int wsel = bx / 12;
    const int nt = bx - wsel * 12;
    const int n0 = nt * 128;
    const int ys = blockIdx.y;
    const int str = (ys >= 10) ? 1 : 0;
    const int m0g = (ys - str * 10) * 128;
    const bool istxt = (m0g >= IMG);
    const int widx = str * 6 + wsel + (istxt ? 3 : 0);
    const ushort* X  = p.Xb + (size_t)str * SD;
    const ushort* img0 = p.Wimg + (((size_t)widx * NTIL + nt) * KTIL) * TILE_USH;
    const void* Bp = p.B[widx];
    const int yidx = str * 3 + wsel;
    float*  Y  = p.Y[yidx];
    ushort* yh = p.Yh[yidx];
    ushort* yl = p.Yl[yidx];

    const int t = threadIdx.x;
    const int wave = t >> 6, lane = t & 63;
    const int quad = lane >> 4, l16 = lane & 15;
    const int wm = (wave >> 1) * 64, wn = (wave & 1) * 64;

    const int arow = t >> 1, apair = t & 1;
    const int aps = apair ^ ((arow >> 3) & 1);
    const int adst = arow * LSTR + aps * 16;

    f32x4 acc[4][4];
#pragma unroll
    for (int i = 0; i < 4; ++i)
#pragma unroll
        for (int j = 0; j < 4; ++j) acc[i][j] = (f32x4)(0.0f);

    uint4 rau[2];
    uint4 rbu[2];

    auto loadA = [&](int k0) {
        const ushort* xp = X + (size_t)(m0g + arow) * DIM + k0 + apair * 16;
        rau[0] = *(const uint4*)xp;
        rau[1] = *(const uint4*)(xp + 8);
    };
    auto loadB = [&](int k0) {
        const ushort* ip = img0 + (size_t)(k0 >> 5) * TILE_USH + t * 8;
        rbu[0] = *(const uint4*)ip;
        rbu[1] = *(const uint4*)(ip + 2048);
    };
    auto storeA = [&](int buf) {
        *(uint4*)&As[buf][adst]     = rau[0];
        *(uint4*)&As[buf][adst + 8] = rau[1];
    };
    auto storeB = [&](int buf) {
        *(uint4*)&Bs[buf][t * 8]        = rbu[0];
        *(uint4*)&Bs[buf][2048 + t * 8] = rbu[1];
    };

    loadA(0); loadB(0);
    storeA(0); storeB(0);
    __syncthreads();

    for (int k = 0; k < DIM / 32; ++k) {
        const int cur = k & 1;
        const bool hn = (k + 1) < DIM / 32;
        if (hn) { loadA((k + 1) * 32); loadB((k + 1) * 32); }

        short8 b[4];
#pragma unroll
        for (int j = 0; j < 4; ++j) {
            const int rrn = wn + j * 16 + l16;
            const int R = rrn & 63, half = rrn >> 6;
            const int gx = (((half << 2) + quad) ^ (R & 7) ^ (R >> 3)) & 7;
            b[j] = *(const short8*)&Bs[cur][R * 64 + gx * 8];
        }
#pragma unroll
        for (int i = 0; i < 4; ++i) {
            const int rr = wm + i * 16 + l16;
            const int ps = (quad >> 1) ^ ((rr >> 3) & 1);
            const int col = ps * 16 + (quad & 1) * 8;
            short8 a = *(const short8*)&As[cur][rr * LSTR + col];
#pragma unroll
            for (int j = 0; j < 4; ++j)
                acc[i][j] = __builtin_amdgcn_mfma_f32_16x16x32_bf16(a, b[j], acc[i][j], 0, 0, 0);
        }
        if (hn) { storeA(cur ^ 1); storeB(cur ^ 1); }
        __syncthreads();
    }

#pragma unroll
    for (int j = 0; j < 4; ++j) {
        const int col = n0 + wn + j * 16 + l16;
        const float bv = dt ? ((const float*)Bp)[col] : bf2f(((const ushort*)Bp)[col]);
#pragma unroll
        for (int i = 0; i < 4; ++i)
#pragma unroll
            for (int r = 0; r < 4; ++r) {
                const int row = m0g + wm + i * 16 + quad * 4 + r;
                const size_t o = (size_t)row * DIM + col;
                const float val = acc[i][j][r] + bv;
                if (Y) Y[o] = val;
                if (yh) {
                    const ushort hv = f2bf(val);
                    yh[o] = hv;
                    yl[o] = f2bf(val - bf2f(hv));
                }
            }
    }
}

// ===========================================================================
// Output projections from pre-split bf16 A planes and pre-imaged weights.
// grid (12, 40), 64-row m-tiles. Segments: mt<16 a_out, <20 a_addout,
// <36 c_out, else c_addout -> widx 12..15.
// ===========================================================================
struct OutP {
    const ushort* Xh; const ushort* Xl;
    const ushort* Wimg;
    const void* B[4];
    void* out;
};

__global__ __launch_bounds__(256) void gemm_out_v5(OutP p, const int* __restrict__ dflag)
{
    __shared__ __align__(16) ushort Ah[2][64 * LSTR];
    __shared__ __align__(16) ushort Al[2][64 * LSTR];
    __shared__ __align__(16) ushort Bs[2][64 * 64];
    const int dt = dflag[0];
    const int nt = blockIdx.x;
    const int n0 = nt * 128;
    const int mt = blockIdx.y;
    const int seg = (mt < 16) ? 0 : (mt < 20) ? 1 : (mt < 36) ? 2 : 3;
    const ushort* img0 = p.Wimg + (((size_t)(12 + seg) * NTIL + nt) * KTIL) * TILE_USH;
    const void* Bp = p.B[seg];
    const int m0 = mt * 64;

    const int t = threadIdx.x;
    const int wave = t >> 6, lane = t & 63;
    const int quad = lane >> 4, l16 = lane & 15;
    const int wm = (wave >> 1) * 32, wn = (wave & 1) * 64;

    const int arow = t >> 2, ag = t & 3;
    const int apg = ag >> 1, asub = ag & 1;
    const int aps = apg ^ ((arow >> 3) & 1);
    const int adst = arow * LSTR + aps * 16 + asub * 8;

    f32x4 acc[2][4];
#pragma unroll
    for (int i = 0; i < 2; ++i)
#pragma unroll
        for (int j = 0; j < 4; ++j) acc[i][j] = (f32x4)(0.0f);

    uint4 rah, ral;
    uint4 rbu[2];

    auto loadA = [&](int k0) {
        const size_t off = (size_t)(m0 + arow) * DIM + k0 + ag * 8;
        rah = *(const uint4*)(p.Xh + off);
        ral = *(const uint4*)(p.Xl + off);
    };
    auto loadB = [&](int k0) {
        const ushort* ip = img0 + (size_t)(k0 >> 5) * TILE_USH + t * 8;
        rbu[0] = *(const uint4*)ip;
        rbu[1] = *(const uint4*)(ip + 2048);
    };
    auto storeA = [&](int buf) {
        *(uint4*)&Ah[buf][adst] = rah;
        *(uint4*)&Al[buf][adst] = ral;
    };
    auto storeB = [&](int buf) {
        *(uint4*)&Bs[buf][t * 8]        = rbu[0];
        *(uint4*)&Bs[buf][2048 + t * 8] = rbu[1];
    };

    loadA(0); loadB(0);
    storeA(0); storeB(0);
    __syncthreads();

    for (int k = 0; k < DIM / 32; ++k) {
        const int cur = k & 1;
        const bool hn = (k + 1) < DIM / 32;
        if (hn) { loadA((k + 1) * 32); loadB((k + 1) * 32); }

        short8 b[4];
#pragma unroll
        for (int j = 0; j < 4; ++j) {
            const int rrn = wn + j * 16 + l16;
            const int R = rrn & 63, half = rrn >> 6;
            const int gx = (((half << 2) + quad) ^ (R & 7) ^ (R >> 3)) & 7;
            b[j] = *(const short8*)&Bs[cur][R * 64 + gx * 8];
        }
#pragma unroll
        for (int i = 0; i < 2; ++i) {
            const int rr = wm + i * 16 + l16;
            const int ps = (quad >> 1) ^ ((rr >> 3) & 1);
            const int col = ps * 16 + (quad & 1) * 8;
            short8 ah = *(const short8*)&Ah[cur][rr * LSTR + col];
            short8 al = *(const short8*)&Al[cur][rr * LSTR + col];
#pragma unroll
            for (int j = 0; j < 4; ++j) {
                acc[i][j] = __builtin_amdgcn_mfma_f32_16x16x32_bf16(ah, b[j], acc[i][j], 0, 0, 0);
                acc[i][j] = __builtin_amdgcn_mfma_f32_16x16x32_bf16(al, b[j], acc[i][j], 0, 0, 0);
            }
        }
        if (hn) { storeA(cur ^ 1); storeB(cur ^ 1); }
        __syncthreads();
    }

#pragma unroll
    for (int j = 0; j < 4; ++j) {
        const int col = n0 + wn + j * 16 + l16;
        const float bv = dt ? ((const float*)Bp)[col] : bf2f(((const ushort*)Bp)[col]);
#pragma unroll
        for (int i = 0; i < 2; ++i)
#pragma unroll
            for (int r = 0; r < 4; ++r) {
                const int grow = m0 + wm + i * 16 + quad * 4 + r;
                const size_t o = (size_t)grow * DIM + col;
                const float val = acc[i][j][r] + bv;
                if (dt) ((float*)p.out)[o] = val;
                else    ((ushort*)p.out)[o] = f2bf(val);
            }
    }
}

// ---------------------------------------------------------------------------
// Fused prep: vtrans (both streams) + all three RoPE jobs in one launch.
// ---------------------------------------------------------------------------
__device__ __forceinline__ void pe_load(const void* pe, int dt, size_t off,
                                        float& c00, float& c01, float& c10, float& c11)
{
    if (dt) {
        float4 pv = *(const float4*)((const float*)pe + off);
        c00 = pv.x; c01 = pv.y; c10 = pv.z; c11 = pv.w;
    } else {
        const ushort* pp = (const ushort*)pe + off;
        c00 = bf2f(pp[0]); c01 = bf2f(pp[1]); c10 = bf2f(pp[2]); c11 = bf2f(pp[3]);
    }
}

struct PrepP {
    const float* v1; const float* vC;
    ushort *vthA, *vtlA, *vthC, *vtlC;
    float* q1;
    const float* k1; ushort *khC, *kloC;
    const void* i2q; float* qx;
    const void* pe;
};

#define VT_BLKS 960
#define RN0 (SEQ * 768)
#define RN1 (SEQ * 768)
#define RN2 (IMG * 768)

__global__ __launch_bounds__(256) void prep_fused(PrepP p, const int* __restrict__ dflag)
{
    __shared__ unsigned int tile[64 * 65];
    const int dt = dflag[0];
    const int bx = blockIdx.x;
    const int t = threadIdx.x;

    if (bx < VT_BLKS) {
        const int z = bx / 480, rem = bx - z * 480;
        const int s0 = (rem % 20) * 64, h = rem / 20;
        const float* V = z ? p.vC : p.v1;
        ushort* Vth = z ? p.vthC : p.vthA;
        ushort* Vtl = z ? p.vtlC : p.vtlA;
#pragma unroll
        for (int it = 0; it < 16; ++it) {
            const int sl = (t >> 6) + (it << 2);
            const int d = t & 63;
            const float v = V[(size_t)(s0 + sl) * DIM + h * HD + d];
            const ushort hv = f2bf(v);
            const ushort lv = f2bf(v - bf2f(hv));
            tile[d * 65 + sl] = (unsigned int)hv | ((unsigned int)lv << 16);
        }
        __syncthreads();
        const int d = t >> 2, cc = (t & 3) << 4;
        ushort th[16], tl[16];
#pragma unroll
        for (int j = 0; j < 16; ++j) {
            const unsigned int w = tile[d * 65 + cc + j];
            th[j] = (ushort)w;
            tl[j] = (ushort)(w >> 16);
        }
        const size_t off = (size_t)(h * HD + d) * SEQ + s0 + cc;
        *(uint4*)(Vth + off)     = *(uint4*)&th[0];
        *(uint4*)(Vth + off + 8) = *(uint4*)&th[8];
        *(uint4*)(Vtl + off)     = *(uint4*)&tl[0];
        *(uint4*)(Vtl + off + 8) = *(uint4*)&tl[8];
        return;
    }

    int idx = (bx - VT_BLKS) * 256 + t;
    if (idx < RN0) {
        int s = idx / 768, pp = idx - s * 768;
        int col = pp << 1, i = pp & 31;
        float* bp = p.q1 + (size_t)s * DIM + col;
        float x0 = bp[0], x1 = bp[1];
        float c00, c01, c10, c11;
        pe_load(p.pe, dt, (size_t)s * 128 + i * 4, c00, c01, c10, c11);
        bp[0] = c00 * x0 + c01 * x1;
        bp[1] = c10 * x0 + c11 * x1;
        return;
    }
    idx -= RN0;
    if (idx < RN1) {
        int s = idx / 768, pp = idx - s * 768;
        int col = pp << 1, i = pp & 31;
        float2 xv = *(const float2*)(p.k1 + (size_t)s * DIM + col);
        float c00, c01, c10, c11;
        pe_load(p.pe, dt, (size_t)s * 128 + i * 4, c00, c01, c10, c11);
        float y0 = c00 * xv.x + c01 * xv.y;
        float y1 = c10 * xv.x + c11 * xv.y;
        ushort h0 = f2bf(y0), h1 = f2bf(y1);
        ushort l0 = f2bf(y0 - bf2f(h0)), l1 = f2bf(y1 - bf2f(h1));
        *(unsigned int*)(p.khC  + (size_t)s * DIM + col) = (unsigned int)h0 | ((unsigned int)h1 << 16);
        *(unsigned int*)(p.kloC + (size_t)s * DIM + col) = (unsigned int)l0 | ((unsigned int)l1 << 16);
        return;
    }
    idx -= RN1;
    if (idx < RN2) {
        int s = idx / 768, pp = idx - s * 768;
        int col = pp << 1, i = pp & 31;
        float x0, x1;
        if (dt) {
            float2 xv = *(const float2*)((const float*)p.i2q + (size_t)s * DIM + col);
            x0 = xv.x; x1 = xv.y;
        } else {
            const ushort* sp = (const ushort*)p.i2q + (size_t)s * DIM + col;
            x0 = bf2f(sp[0]); x1 = bf2f(sp[1]);
        }
        float c00, c01, c10, c11;
        pe_load(p.pe, dt, (size_t)s * 128 + i * 4, c00, c01, c10, c11);
        float* dp = p.qx + (size_t)s * DIM + col;
        dp[0] = c00 * x0 + c01 * x1;
        dp[1] = c10 * x0 + c11 * x1;
    }
}

// ---------------------------------------------------------------------------
// MFMA flash attention, all three attentions in one launch. grid (56, NH, 2).
// v7: 32KB LDS (Q staged through the K planes; P overwrites K after QK^T,
// guarded by one extra barrier) -> 5 blocks/CU instead of 3.
// ---------------------------------------------------------------------------
__device__ __forceinline__ int swz(int row, int col) {
    return row * 64 + ((((col >> 3) ^ row) & 7) << 3) + (col & 7);
}
__device__ __forceinline__ short8 ldfrag(const ushort* plane, int row, int col) {
    return *(const short8*)&plane[swz(row, col)];
}

struct AttnAllP {
    const float* Qf[3];
    const ushort* Kh[3]; const ushort* Kl[3];
    const ushort* Vth[3]; const ushort* Vtl[3];
    float* Op0[3]; float* Op1[3];
    float2* Ml[3];
    int mlq[3];
};

__global__ __launch_bounds__(256) void attn_all(AttnAllP p)
{
    __shared__ ushort Kh_[4096], Kl_[4096];   // K tiles; P after QK^T; Q at start
    __shared__ ushort Vh_[4096], Vl_[4096];

    const int bx = blockIdx.x;
    const int seg = (bx < 20) ? 0 : (bx < 40) ? 1 : 2;
    const int q0 = (bx - ((seg == 0) ? 0 : (seg == 1) ? 20 : 40)) * 64;
    const int h = blockIdx.y;
    const int z = blockIdx.z;
    const int t = threadIdx.x;
    const int wave = t >> 6, lane = t & 63;
    const int quad = lane >> 4, l16 = lane & 15;
    const int wq0 = wave * 16;

    const float* Qf = p.Qf[seg];
    const ushort* Kh = p.Kh[seg]; const ushort* Kl = p.Kl[seg];
    const ushort* Vth = p.Vth[seg]; const ushort* Vtl = p.Vtl[seg];

    const int srow = t >> 2, c0 = (t & 3) << 4;
    const int g0 = c0 >> 3;
    const int p0 = ((g0 ^ (srow & 7)) & 7) << 3;
    const int p1 = (((g0 + 1) ^ (srow & 7)) & 7) << 3;

    // ---- Q staging through the K planes (0.125 scale folded in, exact pow2) ----
    {
        const float* src = Qf + (size_t)(q0 + srow) * DIM + h * HD + c0;
        float x[16];
        *(float4*)&x[0]  = *(const float4*)(src);
        *(float4*)&x[4]  = *(const float4*)(src + 4);
        *(float4*)&x[8]  = *(const float4*)(src + 8);
        *(float4*)&x[12] = *(const float4*)(src + 12);
        ushort hi[16], lo[16];
#pragma unroll
        for (int i = 0; i < 16; ++i) {
            const float xs = x[i] * 0.125f;
            hi[i] = f2bf(xs);
            lo[i] = f2bf(xs - bf2f(hi[i]));
        }
        *(uint4*)&Kh_[srow * 64 + p0] = *(uint4*)&hi[0];
        *(uint4*)&Kh_[srow * 64 + p1] = *(uint4*)&hi[8];
        *(uint4*)&Kl_[srow * 64 + p0] = *(uint4*)&lo[0];
        *(uint4*)&Kl_[srow * 64 + p1] = *(uint4*)&lo[8];
    }
    // Within-wave store->read (wave stages its own 16 rows; no barrier).
    short8 qfh[2], qfl[2];
#pragma unroll
    for (int c = 0; c < 2; ++c) {
        qfh[c] = ldfrag(Kh_, wq0 + l16, c * 32 + quad * 8);
        qfl[c] = ldfrag(Kl_, wq0 + l16, c * 32 + quad * 8);
    }

    float m_[4], l_[4];
#pragma unroll
    for (int r = 0; r < 4; ++r) { m_[r] = -3e38f; l_[r] = 0.0f; }
    f32x4 Oacc[4];
#pragma unroll
    for (int j = 0; j < 4; ++j) Oacc[j] = (f32x4)(0.0f);

    const int kvbeg = z * (SEQ / 2);
    for (int kt = 0; kt < SEQ / 2; kt += 64) {
        const int kv0 = kvbeg + kt;
        __syncthreads();   // Q-frag reads / prev-iter P reads complete
        {
            const size_t off = (size_t)(kv0 + srow) * DIM + h * HD + c0;
            *(uint4*)&Kh_[srow * 64 + p0] = *(const uint4*)(Kh + off);
            *(uint4*)&Kh_[srow * 64 + p1] = *(const uint4*)(Kh + off + 8);
            *(uint4*)&Kl_[srow * 64 + p0] = *(const uint4*)(Kl + off);
            *(uint4*)&Kl_[srow * 64 + p1] = *(const uint4*)(Kl + off + 8);
        }
        {
            const size_t off = (size_t)(h * HD + srow) * SEQ + kv0 + c0;
            *(uint4*)&Vh_[srow * 64 + p0] = *(const uint4*)(Vth + off);
            *(uint4*)&Vh_[srow * 64 + p1] = *(const uint4*)(Vth + off + 8);
            *(uint4*)&Vl_[srow * 64 + p0] = *(const uint4*)(Vtl + off);
            *(uint4*)&Vl_[srow * 64 + p1] = *(const uint4*)(Vtl + off + 8);
        }
        __syncthreads();

        f32x4 S[4];
#pragma unroll
        for (int j = 0; j < 4; ++j) S[j] = (f32x4)(0.0f);
        __builtin_amdgcn_s_setprio(1);
#pragma unroll
        for (int c = 0; c < 2; ++c) {
#pragma unroll
            for (int j = 0; j < 4; ++j) {
                short8 bh = ldfrag(Kh_, j * 16 + l16, c * 32 + quad * 8);
                short8 bl = ldfrag(Kl_, j * 16 + l16, c * 32 + quad * 8);
                S[j] = __builtin_amdgcn_mfma_f32_16x16x32_bf16(qfh[c], bh, S[j], 0, 0, 0);
                S[j] = __builtin_amdgcn_mfma_f32_16x16x32_bf16(qfl[c], bh, S[j], 0, 0, 0);
                S[j] = __builtin_amdgcn_mfma_f32_16x16x32_bf16(qfh[c], bl, S[j], 0, 0, 0);
            }
        }
        __builtin_amdgcn_s_setprio(0);

        float alpha[4];
#pragma unroll
        for (int r = 0; r < 4; ++r) {
            float mx = fmaxf(fmaxf(S[0][r], S[1][r]), fmaxf(S[2][r], S[3][r]));
            mx = fmaxf(mx, __shfl_xor(mx, 1));
            mx = fmaxf(mx, __shfl_xor(mx, 2));
            mx = fmaxf(mx, __shfl_xor(mx, 4));
            mx = fmaxf(mx, __shfl_xor(mx, 8));
            float mn = fmaxf(m_[r], mx);
            alpha[r] = __expf(m_[r] - mn);
            m_[r] = mn;
            float rs = 0.0f;
#pragma unroll
            for (int j = 0; j < 4; ++j) {
                float pv = __expf(S[j][r] - mn);
                S[j][r] = pv;
                rs += pv;
            }
            rs += __shfl_xor(rs, 1);
            rs += __shfl_xor(rs, 2);
            rs += __shfl_xor(rs, 4);
            rs += __shfl_xor(rs, 8);
            l_[r] = l_[r] * alpha[r] + rs;
        }
#pragma unroll
        for (int j = 0; j < 4; ++j)
#pragma unroll
            for (int r = 0; r < 4; ++r) Oacc[j][r] *= alpha[r];

        __syncthreads();   // all waves done reading K before P overwrites it

        {
            const int prow = wq0 + quad * 4;
#pragma unroll
            for (int j = 0; j < 4; ++j)
#pragma unroll
                for (int r = 0; r < 4; ++r) {
                    float pv = S[j][r];
                    ushort ph = f2bf(pv);
                    ushort pl = f2bf_rz(pv - bf2f(ph));
                    int idx = swz(prow + r, j * 16 + l16);
                    Kh_[idx] = ph;
                    Kl_[idx] = pl;
                }
        }

        __builtin_amdgcn_s_setprio(1);
#pragma unroll
        for (int c = 0; c < 2; ++c) {
            short8 pah = ldfrag(Kh_, wq0 + l16, c * 32 + quad * 8);
            short8 pal = ldfrag(Kl_, wq0 + l16, c * 32 + quad * 8);
#pragma unroll
            for (int jn = 0; jn < 4; ++jn) {
                short8 vbh = ldfrag(Vh_, jn * 16 + l16, c * 32 + quad * 8);
                short8 vbl = ldfrag(Vl_, jn * 16 + l16, c * 32 + quad * 8);
                Oacc[jn] = __builtin_amdgcn_mfma_f32_16x16x32_bf16(pah, vbh, Oacc[jn], 0, 0, 0);
                Oacc[jn] = __builtin_amdgcn_mfma_f32_16x16x32_bf16(pal, vbh, Oacc[jn], 0, 0, 0);
                Oacc[jn] = __builtin_amdgcn_mfma_f32_16x16x32_bf16(pah, vbl, Oacc[jn], 0, 0, 0);
            }
        }
        __builtin_amdgcn_s_setprio(0);
    }

    float* Opz = z ? p.Op1[seg] : p.Op0[seg];
    const int mlq = p.mlq[seg];
    float2* Ml = p.Ml[seg];
#pragma unroll
    for (int r = 0; r < 4; ++r) {
        const int rowq = q0 + wq0 + quad * 4 + r;
        if (l16 == 0)
            Ml[((size_t)z * NH + h) * mlq + rowq] = make_float2(m_[r], l_[r]);
#pragma unroll
        for (int jn = 0; jn < 4; ++jn)
            Opz[(size_t)rowq * DIM + h * HD + jn * 16 + l16] = Oacc[jn][r];
    }
}

// ---------------------------------------------------------------------------
// Unified merge: combines z-partials for A/C/X, folds cross residual into A,
// emits the out-proj A operand as bf16 hi/lo planes (2560 rows).
// ---------------------------------------------------------------------------
struct MergeP {
    const float *pA0, *pA1, *pC0, *pC1, *pX0, *pX1;
    const float2 *MlA, *MlC, *MlX;
    ushort *Xh, *Xl;
};

__device__ __forceinline__ float4 comb2(const float* O0, const float* O1,
                                        const float2* Ml, int mlq, int row, int c4)
{
    const int h = c4 >> 6;
    const float2 a = Ml[(size_t)h * mlq + row];
    const float2 b = Ml[(size_t)(NH + h) * mlq + row];
    const float ms = fmaxf(a.x, b.x);
    const float s0 = __expf(a.x - ms), s1 = __expf(b.x - ms);
    const float inv = 1.0f / (s0 * a.y + s1 * b.y);
    const float4 o0 = *(const float4*)&O0[(size_t)row * DIM + c4];
    const float4 o1 = *(const float4*)&O1[(size_t)row * DIM + c4];
    float4 r;
    r.x = (s0 * o0.x + s1 * o1.x) * inv;
    r.y = (s0 * o0.y + s1 * o1.y) * inv;
    r.z = (s0 * o0.z + s1 * o1.z) * inv;
    r.w = (s0 * o0.w + s1 * o1.w) * inv;
    return r;
}

__global__ __launch_bounds__(256) void merge_all(MergeP p)
{
    const int idx = blockIdx.x * 256 + threadIdx.x;
    if (idx >= 2560 * 384) return;
    const int row = idx / 384;
    const int c4 = (idx - row * 384) << 2;
    float4 r;
    if (row < SEQ) {
        r = comb2(p.pA0, p.pA1, p.MlA, SEQ, row, c4);
        if (row < IMG) {
            const float4 x = comb2(p.pX0, p.pX1, p.MlX, IMG, row, c4);
            r.x += x.x; r.y += x.y; r.z += x.z; r.w += x.w;
        }
    } else {
        r = comb2(p.pC0, p.pC1, p.MlC, SEQ, row - SEQ, c4);
    }
    float v[4] = {r.x, r.y, r.z, r.w};
    ushort hi[4], lo[4];
#pragma unroll
    for (int j = 0; j < 4; ++j) {
        hi[j] = f2bf(v[j]);
        lo[j] = f2bf(v[j] - bf2f(hi[j]));
    }
    const size_t o = (size_t)row * DIM + c4;
    *(uint2*)(p.Xh + o) = *(uint2*)hi;
    *(uint2*)(p.Xl + o) = *(uint2*)lo;
}

// ---------------------------------------------------------------------------
extern "C" void kernel_launch(void* const* d_in, const int* in_sizes, int n_in,
                              void* d_out, int out_size, void* d_ws, size_t ws_size,
                              hipStream_t stream) {
    (void)in_sizes; (void)n_in; (void)out_size; (void)ws_size;
    const void* hs   = d_in[0];
    const void* ehs  = d_in[1];
    const void* hsc  = d_in[2];
    const void* ehsc = d_in[3];
    const void* i2q  = d_in[4];
    const void* pe   = d_in[5];
#define W_(i) ((const void*)d_in[i])

    char* base = (char*)d_ws;
    int* flag = (int*)base;
    char* ptr = base + 256;
    auto alloc = [&](size_t bytes) { char* r = ptr; ptr += bytes; return r; };
    float* q1  = (float*)alloc(SD * 4);      // C q f32 (roped inplace); later Xl
    float* k1  = (float*)alloc(SD * 4);      // C k f32; later pA1
    float* v1  = (float*)alloc(SD * 4);      // A v f32; later pA0
    float* vC  = (float*)alloc(SD * 4);      // C v f32; later pC0
    float* qA  = (float*)alloc(SD * 4);      // A q f32; later Xh
    float* qx  = (float*)alloc(IDSZ * 4);    // X q f32
    ushort* khA  = (ushort*)alloc(SD * 2);
    ushort* kloA = (ushort*)alloc(SD * 2);
    ushort* vthA = (ushort*)alloc(SD * 2);
    ushort* vtlA = (ushort*)alloc(SD * 2);
    ushort* khC  = (ushort*)alloc(SD * 2);
    ushort* kloC = (ushort*)alloc(SD * 2);
    ushort* vthC = (ushort*)alloc(SD * 2);
    ushort* vtlC = (ushort*)alloc(SD * 2);
    float* pX0 = (float*)alloc(IDSZ * 4);
    float* pX1 = (float*)alloc(IDSZ * 4);
    float2* MlA = (float2*)alloc((size_t)2 * NH * SEQ * 8);
    float2* MlC = (float2*)alloc((size_t)2 * NH * SEQ * 8);
    float2* MlX = (float2*)alloc((size_t)2 * NH * IMG * 8);
    ushort* Wimg = (ushort*)alloc((size_t)16 * NTIL * KTIL * TILE_USH * 2);
    ushort* Xbf = (ushort*)alloc(2 * SD * 2);
    float* pC1 = (float*)Xbf;     // Xbf dead after qkv
    ushort* Xh = (ushort*)qA;     // dead after attn_all
    ushort* Xl = (ushort*)q1;     // dead after attn_all

    dim3 blk(256);
    detect_dtype<<<1, blk, 0, stream>>>(hs, flag);

    // ---- one-time conversions: weight tile images + bf16 X ----
    {
        WImgP wp;
        const int wsrc[16] = {6, 8, 10, 12, 14, 16, 22, 24, 26, 28, 30, 32,
                              18, 20, 34, 36};
        for (int j = 0; j < 16; ++j) wp.src[j] = W_(wsrc[j]);
        wp.img = Wimg;
        convert_wimg<<<dim3(NTIL * KTIL, 16), blk, 0, stream>>>(wp, flag);

        CvtP cp;
        cp.src[0] = hs;   cp.dst[0] = Xbf;             cp.n8[0] = (int)(IDSZ / 8);
        cp.src[1] = ehs;  cp.dst[1] = Xbf + IDSZ;      cp.n8[1] = (int)((size_t)TXT * DIM / 8);
        cp.src[2] = hsc;  cp.dst[2] = Xbf + SD;        cp.n8[2] = (int)(IDSZ / 8);
        cp.src[3] = ehsc; cp.dst[3] = Xbf + SD + IDSZ; cp.n8[3] = (int)((size_t)TXT * DIM / 8);
        convert_bf16<<<dim3((int)(IDSZ / 8 + 255) / 256, 4), blk, 0, stream>>>(cp, flag);
    }

    QKV3P qp;
    qp.Xb = Xbf;
    qp.Wimg = Wimg;
    {
        const int bsrc[12] = {7, 9, 11, 13, 15, 17, 23, 25, 27, 29, 31, 33};
        for (int j = 0; j < 12; ++j) qp.B[j] = W_(bsrc[j]);
    }
    for (int j = 0; j < 6; ++j) { qp.Y[j] = nullptr; qp.Yh[j] = nullptr; qp.Yl[j] = nullptr; }
    qp.Y[0] = qA;
    qp.Yh[1] = khA; qp.Yl[1] = kloA;
    qp.Y[2] = v1;
    qp.Y[3] = q1;
    qp.Y[4] = k1;
    qp.Y[5] = vC;
    gemm_qkv_v5<<<dim3(36, 20), blk, 0, stream>>>(qp, flag);

    {
        PrepP pp;
        pp.v1 = v1; pp.vC = vC;
        pp.vthA = vthA; pp.vtlA = vtlA; pp.vthC = vthC; pp.vtlC = vtlC;
        pp.q1 = q1;
        pp.k1 = k1; pp.khC = khC; pp.kloC = kloC;
        pp.i2q = i2q; pp.qx = qx;
        pp.pe = pe;
        const int ropeBlocks = (RN0 + RN1 + RN2 + 255) / 256;
        prep_fused<<<VT_BLKS + ropeBlocks, blk, 0, stream>>>(pp, flag);
    }

    {
        AttnAllP ap;
        ap.Qf[0] = qA; ap.Qf[1] = q1; ap.Qf[2] = qx;
        ap.Kh[0] = khA; ap.Kl[0] = kloA;
        ap.Kh[1] = khC; ap.Kl[1] = kloC;
        ap.Kh[2] = khC; ap.Kl[2] = kloC;
        ap.Vth[0] = vthA; ap.Vtl[0] = vtlA;
        ap.Vth[1] = vthC; ap.Vtl[1] = vtlC;
        ap.Vth[2] = vthC; ap.Vtl[2] = vtlC;
        ap.Op0[0] = v1;  ap.Op1[0] = k1;
        ap.Op0[1] = vC;  ap.Op1[1] = pC1;
        ap.Op0[2] = pX0; ap.Op1[2] = pX1;
        ap.Ml[0] = MlA; ap.Ml[1] = MlC; ap.Ml[2] = MlX;
        ap.mlq[0] = SEQ; ap.mlq[1] = SEQ; ap.mlq[2] = IMG;
        attn_all<<<dim3(56, NH, 2), blk, 0, stream>>>(ap);
    }

    {
        MergeP mp;
        mp.pA0 = v1; mp.pA1 = k1;
        mp.pC0 = vC; mp.pC1 = pC1;
        mp.pX0 = pX0; mp.pX1 = pX1;
        mp.MlA = MlA; mp.MlC = MlC; mp.MlX = MlX;
        mp.Xh = Xh; mp.Xl = Xl;
        merge_all<<<(2560 * 384 + 255) / 256, blk, 0, stream>>>(mp);
    }

    {
        OutP op;
        op.Xh = Xh; op.Xl = Xl;
        op.Wimg = Wimg;
        op.B[0] = W_(19); op.B[1] = W_(21); op.B[2] = W_(35); op.B[3] = W_(37);
        op.out = d_out;
        gemm_out_v5<<<dim3(12, 40), blk, 0, stream>>>(op, flag);
    }
#undef W_
}

// Round 8
// 555.617 us; speedup vs baseline: 1.1001x; 1.1001x over previous
//
#include <hip/hip_runtime.h>

#define DIM 1536
#define IMG 1024
#define TXT 256
#define SEQ 1280
#define NH 24
#define HD 64
#define SD ((size_t)SEQ * DIM)
#define IDSZ ((size_t)IMG * DIM)
#define WSZ ((size_t)DIM * DIM)

typedef __attribute__((ext_vector_type(8))) short short8;
typedef __attribute__((ext_vector_type(4))) float f32x4;

__device__ __forceinline__ float bf2f(ushort u) {
    union { unsigned int i; float f; } v; v.i = ((unsigned int)u) << 16; return v.f;
}
__device__ __forceinline__ ushort f2bf(float f) {
    union { unsigned int i; float f; } v; v.f = f;
    unsigned int u = v.i;
    u += 0x7fffu + ((u >> 16) & 1u);
    return (ushort)(u >> 16);
}
// Truncating f32 -> bf16 for lo-residual planes only.
__device__ __forceinline__ ushort f2bf_rz(float f) {
    union { unsigned int i; float f; } v; v.f = f;
    return (ushort)(v.i >> 16);
}

// ---------------------------------------------------------------------------
// Input-dtype detector (flag=1 -> fp32 underneath, flag=0 -> bf16).
// ---------------------------------------------------------------------------
__global__ __launch_bounds__(256) void detect_dtype(const void* __restrict__ p,
                                                    int* __restrict__ flag)
{
    __shared__ int cnt;
    if (threadIdx.x == 0) cnt = 0;
    __syncthreads();
    const ushort* u = (const ushort*)p;
    int local = 0;
    for (int i = threadIdx.x; i < 2048; i += 256) {
        ushort v = u[2 * i];
        int e = (v >> 7) & 0xFF;
        if (e >= 0xC0) local++;
    }
    atomicAdd(&cnt, local);
    __syncthreads();
    if (threadIdx.x == 0) flag[0] = (cnt > 16) ? 1 : 0;
}

// ---------------------------------------------------------------------------
// One-time bf16 conversion: 16 weights (12 qkv + 4 out) + 4 X inputs.
// ---------------------------------------------------------------------------
struct CvtP {
    const void* src[20];
    ushort* dst[20];
    int n8[20];
};

__global__ __launch_bounds__(256) void convert_bf16(CvtP p, const int* __restrict__ dflag)
{
    const int a = blockIdx.y;
    const int i = blockIdx.x * 256 + threadIdx.x;
    if (i >= p.n8[a]) return;
    const size_t off = (size_t)i * 8;
    uint4 o;
    if (dflag[0]) {
        const float* s = (const float*)p.src[a] + off;
        const float4 f0 = *(const float4*)s;
        const float4 f1 = *(const float4*)(s + 4);
        ushort t[8];
        t[0] = f2bf(f0.x); t[1] = f2bf(f0.y); t[2] = f2bf(f0.z); t[3] = f2bf(f0.w);
        t[4] = f2bf(f1.x); t[5] = f2bf(f1.y); t[6] = f2bf(f1.z); t[7] = f2bf(f1.w);
        o = *(uint4*)t;
    } else {
        o = *(const uint4*)((const ushort*)p.src[a] + off);
    }
    *(uint4*)(p.dst[a] + off) = o;
}

#define LSTR 40

// ===========================================================================
// Merged QKV GEMM over pre-converted bf16 X and W. grid (36, 20).
// B plane: 128 n-rows folded into 64 LDS rows of 64 ushorts, granule XOR
// gx = ((half<<2)+g) ^ (R&7) ^ (R>>3).
// ===========================================================================
struct QKV3P {
    const ushort* Xb;    // [2][SEQ][DIM] bf16
    const ushort* Wb;    // [16][DIM][DIM] bf16; qkv uses idx 0..11
    const void* B[12];
    float* Y[6];
    ushort* Yh[6];
    ushort* Yl[6];
};

__global__ __launch_bounds__(256) void gemm_qkv_v4(QKV3P p, const int* __restrict__ dflag)
{
    __shared__ __align__(16) ushort As[2][128 * LSTR];
    __shared__ __align__(16) ushort Bs[2][64 * 64];
    const int dt = dflag[0];
    const int bx = blockIdx.x;
    const int wsel = bx / 12;
    const int n0 = (bx - wsel * 12) * 128;
    const int ys = blockIdx.y;
    const int str = (ys >= 10) ? 1 : 0;
    const int m0g = (ys - str * 10) * 128;
    const bool istxt = (m0g >= IMG);
    const int widx = str * 6 + wsel + (istxt ? 3 : 0);
    const ushort* X  = p.Xb + (size_t)str * SD;
    const ushort* Wp = p.Wb + (size_t)widx * WSZ;
    const void* Bp = p.B[widx];
    const int yidx = str * 3 + wsel;
    float*  Y  = p.Y[yidx];
    ushort* yh = p.Yh[yidx];
    ushort* yl = p.Yl[yidx];

    const int t = threadIdx.x;
    const int wave = t >> 6, lane = t & 63;
    const int quad = lane >> 4, l16 = lane & 15;
    const int wm = (wave >> 1) * 64, wn = (wave & 1) * 64;

    const int arow = t >> 1, apair = t & 1;
    const int bn8 = (t & 15) << 3, bkk = (t >> 4) << 1;
    const int aps = apair ^ ((arow >> 3) & 1);
    const int adst = arow * LSTR + aps * 16;
    const int bkg = bkk >> 3, bo = bkk & 7;

    f32x4 acc[4][4];
#pragma unroll
    for (int i = 0; i < 4; ++i)
#pragma unroll
        for (int j = 0; j < 4; ++j) acc[i][j] = (f32x4)(0.0f);

    uint4 rau[2];
    uint4 rbu[2];

    auto loadA = [&](int k0) {
        const ushort* xp = X + (size_t)(m0g + arow) * DIM + k0 + apair * 16;
        rau[0] = *(const uint4*)xp;
        rau[1] = *(const uint4*)(xp + 8);
    };
    auto loadB = [&](int k0) {
        const ushort* wp0 = Wp + (size_t)(k0 + bkk) * DIM + n0 + bn8;
        rbu[0] = *(const uint4*)wp0;
        rbu[1] = *(const uint4*)(wp0 + DIM);
    };
    auto storeA = [&](int buf) {
        *(uint4*)&As[buf][adst]     = rau[0];
        *(uint4*)&As[buf][adst + 8] = rau[1];
    };
    auto storeB = [&](int buf) {
        ushort t0[8], t1[8];
        *(uint4*)t0 = rbu[0];
        *(uint4*)t1 = rbu[1];
#pragma unroll
        for (int j = 0; j < 8; ++j) {
            const int rr = bn8 + j;
            const int R = rr & 63, half = rr >> 6;
            const int gx = (((half << 2) + bkg) ^ (R & 7) ^ (R >> 3)) & 7;
            *(unsigned int*)&Bs[buf][R * 64 + gx * 8 + bo] =
                (unsigned int)t0[j] | ((unsigned int)t1[j] << 16);
        }
    };

    loadA(0); loadB(0);
    storeA(0); storeB(0);
    __syncthreads();

    for (int k = 0; k < DIM / 32; ++k) {
        const int cur = k & 1;
        const bool hn = (k + 1) < DIM / 32;
        if (hn) { loadA((k + 1) * 32); loadB((k + 1) * 32); }

        short8 b[4];
#pragma unroll
        for (int j = 0; j < 4; ++j) {
            const int rrn = wn + j * 16 + l16;
            const int R = rrn & 63, half = rrn >> 6;
            const int gx = (((half << 2) + quad) ^ (R & 7) ^ (R >> 3)) & 7;
            b[j] = *(const short8*)&Bs[cur][R * 64 + gx * 8];
        }
#pragma unroll
        for (int i = 0; i < 4; ++i) {
            const int rr = wm + i * 16 + l16;
            const int ps = (quad >> 1) ^ ((rr >> 3) & 1);
            const int col = ps * 16 + (quad & 1) * 8;
            short8 a = *(const short8*)&As[cur][rr * LSTR + col];
#pragma unroll
            for (int j = 0; j < 4; ++j)
                acc[i][j] = __builtin_amdgcn_mfma_f32_16x16x32_bf16(a, b[j], acc[i][j], 0, 0, 0);
        }
        if (hn) { storeA(cur ^ 1); storeB(cur ^ 1); }
        __syncthreads();
    }

#pragma unroll
    for (int j = 0; j < 4; ++j) {
        const int col = n0 + wn + j * 16 + l16;
        const float bv = dt ? ((const float*)Bp)[col] : bf2f(((const ushort*)Bp)[col]);
#pragma unroll
        for (int i = 0; i < 4; ++i)
#pragma unroll
            for (int r = 0; r < 4; ++r) {
                const int row = m0g + wm + i * 16 + quad * 4 + r;
                const size_t o = (size_t)row * DIM + col;
                const float val = acc[i][j][r] + bv;
                if (Y) Y[o] = val;
                if (yh) {
                    const ushort hv = f2bf(val);
                    yh[o] = hv;
                    yl[o] = f2bf(val - bf2f(hv));
                }
            }
    }
}

// ===========================================================================
// Output projections from pre-split bf16 A planes (Xh/Xl, 2560 rows) and
// pre-converted bf16 weights (idx 12..15). grid (12, 40), 64-row m-tiles.
// ===========================================================================
struct OutP {
    const ushort* Xh; const ushort* Xl;
    const ushort* Wb;    // 4 * WSZ bf16
    const void* B[4];
    void* out;
};

__global__ __launch_bounds__(256) void gemm_out_v4(OutP p, const int* __restrict__ dflag)
{
    __shared__ __align__(16) ushort Ah[2][64 * LSTR];
    __shared__ __align__(16) ushort Al[2][64 * LSTR];
    __shared__ __align__(16) ushort Bs[2][64 * 64];
    const int dt = dflag[0];
    const int n0 = blockIdx.x * 128;
    const int mt = blockIdx.y;
    const int seg = (mt < 16) ? 0 : (mt < 20) ? 1 : (mt < 36) ? 2 : 3;
    const ushort* Wp = p.Wb + (size_t)seg * WSZ;
    const void* Bp = p.B[seg];
    const int m0 = mt * 64;

    const int t = threadIdx.x;
    const int wave = t >> 6, lane = t & 63;
    const int quad = lane >> 4, l16 = lane & 15;
    const int wm = (wave >> 1) * 32, wn = (wave & 1) * 64;

    const int arow = t >> 2, ag = t & 3;
    const int apg = ag >> 1, asub = ag & 1;
    const int aps = apg ^ ((arow >> 3) & 1);
    const int adst = arow * LSTR + aps * 16 + asub * 8;
    const int bn8 = (t & 15) << 3, bkk = (t >> 4) << 1;
    const int bkg = bkk >> 3, bo = bkk & 7;

    f32x4 acc[2][4];
#pragma unroll
    for (int i = 0; i < 2; ++i)
#pragma unroll
        for (int j = 0; j < 4; ++j) acc[i][j] = (f32x4)(0.0f);

    uint4 rah, ral;
    uint4 rbu[2];

    auto loadA = [&](int k0) {
        const size_t off = (size_t)(m0 + arow) * DIM + k0 + ag * 8;
        rah = *(const uint4*)(p.Xh + off);
        ral = *(const uint4*)(p.Xl + off);
    };
    auto loadB = [&](int k0) {
        const ushort* wp0 = Wp + (size_t)(k0 + bkk) * DIM + n0 + bn8;
        rbu[0] = *(const uint4*)wp0;
        rbu[1] = *(const uint4*)(wp0 + DIM);
    };
    auto storeA = [&](int buf) {
        *(uint4*)&Ah[buf][adst] = rah;
        *(uint4*)&Al[buf][adst] = ral;
    };
    auto storeB = [&](int buf) {
        ushort t0[8], t1[8];
        *(uint4*)t0 = rbu[0];
        *(uint4*)t1 = rbu[1];
#pragma unroll
        for (int j = 0; j < 8; ++j) {
            const int rr = bn8 + j;
            const int R = rr & 63, half = rr >> 6;
            const int gx = (((half << 2) + bkg) ^ (R & 7) ^ (R >> 3)) & 7;
            *(unsigned int*)&Bs[buf][R * 64 + gx * 8 + bo] =
                (unsigned int)t0[j] | ((unsigned int)t1[j] << 16);
        }
    };

    loadA(0); loadB(0);
    storeA(0); storeB(0);
    __syncthreads();

    for (int k = 0; k < DIM / 32; ++k) {
        const int cur = k & 1;
        const bool hn = (k + 1) < DIM / 32;
        if (hn) { loadA((k + 1) * 32); loadB((k + 1) * 32); }

        short8 b[4];
#pragma unroll
        for (int j = 0; j < 4; ++j) {
            const int rrn = wn + j * 16 + l16;
            const int R = rrn & 63, half = rrn >> 6;
            const int gx = (((half << 2) + quad) ^ (R & 7) ^ (R >> 3)) & 7;
            b[j] = *(const short8*)&Bs[cur][R * 64 + gx * 8];
        }
#pragma unroll
        for (int i = 0; i < 2; ++i) {
            const int rr = wm + i * 16 + l16;
            const int ps = (quad >> 1) ^ ((rr >> 3) & 1);
            const int col = ps * 16 + (quad & 1) * 8;
            short8 ah = *(const short8*)&Ah[cur][rr * LSTR + col];
            short8 al = *(const short8*)&Al[cur][rr * LSTR + col];
#pragma unroll
            for (int j = 0; j < 4; ++j) {
                acc[i][j] = __builtin_amdgcn_mfma_f32_16x16x32_bf16(ah, b[j], acc[i][j], 0, 0, 0);
                acc[i][j] = __builtin_amdgcn_mfma_f32_16x16x32_bf16(al, b[j], acc[i][j], 0, 0, 0);
            }
        }
        if (hn) { storeA(cur ^ 1); storeB(cur ^ 1); }
        __syncthreads();
    }

#pragma unroll
    for (int j = 0; j < 4; ++j) {
        const int col = n0 + wn + j * 16 + l16;
        const float bv = dt ? ((const float*)Bp)[col] : bf2f(((const ushort*)Bp)[col]);
#pragma unroll
        for (int i = 0; i < 2; ++i)
#pragma unroll
            for (int r = 0; r < 4; ++r) {
                const int grow = m0 + wm + i * 16 + quad * 4 + r;
                const size_t o = (size_t)grow * DIM + col;
                const float val = acc[i][j][r] + bv;
                if (dt) ((float*)p.out)[o] = val;
                else    ((ushort*)p.out)[o] = f2bf(val);
            }
    }
}

// ---------------------------------------------------------------------------
// Fused prep: vtrans (both streams) + all three RoPE jobs in one launch.
// ---------------------------------------------------------------------------
__device__ __forceinline__ void pe_load(const void* pe, int dt, size_t off,
                                        float& c00, float& c01, float& c10, float& c11)
{
    if (dt) {
        float4 pv = *(const float4*)((const float*)pe + off);
        c00 = pv.x; c01 = pv.y; c10 = pv.z; c11 = pv.w;
    } else {
        const ushort* pp = (const ushort*)pe + off;
        c00 = bf2f(pp[0]); c01 = bf2f(pp[1]); c10 = bf2f(pp[2]); c11 = bf2f(pp[3]);
    }
}

struct PrepP {
    const float* v1; const float* vC;
    ushort *vthA, *vtlA, *vthC, *vtlC;
    float* q1;
    const float* k1; ushort *khC, *kloC;
    const void* i2q; float* qx;
    const void* pe;
};

#define VT_BLKS 960
#define RN0 (SEQ * 768)
#define RN1 (SEQ * 768)
#define RN2 (IMG * 768)

__global__ __launch_bounds__(256) void prep_fused(PrepP p, const int* __restrict__ dflag)
{
    __shared__ unsigned int tile[64 * 65];
    const int dt = dflag[0];
    const int bx = blockIdx.x;
    const int t = threadIdx.x;

    if (bx < VT_BLKS) {
        const int z = bx / 480, rem = bx - z * 480;
        const int s0 = (rem % 20) * 64, h = rem / 20;
        const float* V = z ? p.vC : p.v1;
        ushort* Vth = z ? p.vthC : p.vthA;
        ushort* Vtl = z ? p.vtlC : p.vtlA;
#pragma unroll
        for (int it = 0; it < 16; ++it) {
            const int sl = (t >> 6) + (it << 2);
            const int d = t & 63;
            const float v = V[(size_t)(s0 + sl) * DIM + h * HD + d];
            const ushort hv = f2bf(v);
            const ushort lv = f2bf(v - bf2f(hv));
            tile[d * 65 + sl] = (unsigned int)hv | ((unsigned int)lv << 16);
        }
        __syncthreads();
        const int d = t >> 2, cc = (t & 3) << 4;
        ushort th[16], tl[16];
#pragma unroll
        for (int j = 0; j < 16; ++j) {
            const unsigned int w = tile[d * 65 + cc + j];
            th[j] = (ushort)w;
            tl[j] = (ushort)(w >> 16);
        }
        const size_t off = (size_t)(h * HD + d) * SEQ + s0 + cc;
        *(uint4*)(Vth + off)     = *(uint4*)&th[0];
        *(uint4*)(Vth + off + 8) = *(uint4*)&th[8];
        *(uint4*)(Vtl + off)     = *(uint4*)&tl[0];
        *(uint4*)(Vtl + off + 8) = *(uint4*)&tl[8];
        return;
    }

    int idx = (bx - VT_BLKS) * 256 + t;
    if (idx < RN0) {
        int s = idx / 768, pp = idx - s * 768;
        int col = pp << 1, i = pp & 31;
        float* bp = p.q1 + (size_t)s * DIM + col;
        float x0 = bp[0], x1 = bp[1];
        float c00, c01, c10, c11;
        pe_load(p.pe, dt, (size_t)s * 128 + i * 4, c00, c01, c10, c11);
        bp[0] = c00 * x0 + c01 * x1;
        bp[1] = c10 * x0 + c11 * x1;
        return;
    }
    idx -= RN0;
    if (idx < RN1) {
        int s = idx / 768, pp = idx - s * 768;
        int col = pp << 1, i = pp & 31;
        float2 xv = *(const float2*)(p.k1 + (size_t)s * DIM + col);
        float c00, c01, c10, c11;
        pe_load(p.pe, dt, (size_t)s * 128 + i * 4, c00, c01, c10, c11);
        float y0 = c00 * xv.x + c01 * xv.y;
        float y1 = c10 * xv.x + c11 * xv.y;
        ushort h0 = f2bf(y0), h1 = f2bf(y1);
        ushort l0 = f2bf(y0 - bf2f(h0)), l1 = f2bf(y1 - bf2f(h1));
        *(unsigned int*)(p.khC  + (size_t)s * DIM + col) = (unsigned int)h0 | ((unsigned int)h1 << 16);
        *(unsigned int*)(p.kloC + (size_t)s * DIM + col) = (unsigned int)l0 | ((unsigned int)l1 << 16);
        return;
    }
    idx -= RN1;
    if (idx < RN2) {
        int s = idx / 768, pp = idx - s * 768;
        int col = pp << 1, i = pp & 31;
        float x0, x1;
        if (dt) {
            float2 xv = *(const float2*)((const float*)p.i2q + (size_t)s * DIM + col);
            x0 = xv.x; x1 = xv.y;
        } else {
            const ushort* sp = (const ushort*)p.i2q + (size_t)s * DIM + col;
            x0 = bf2f(sp[0]); x1 = bf2f(sp[1]);
        }
        float c00, c01, c10, c11;
        pe_load(p.pe, dt, (size_t)s * 128 + i * 4, c00, c01, c10, c11);
        float* dp = p.qx + (size_t)s * DIM + col;
        dp[0] = c00 * x0 + c01 * x1;
        dp[1] = c10 * x0 + c11 * x1;
    }
}

// ---------------------------------------------------------------------------
// MFMA flash attention, all three attentions in one launch. grid (56, NH).
// v8 = round-6 structure (48KB LDS, separate Q planes, no extra barrier)
// with NSPLIT removed: each block walks the FULL KV range (single-pass
// online softmax, reference-equivalent) and writes the final normalized O.
// ---------------------------------------------------------------------------
__device__ __forceinline__ int swz(int row, int col) {
    return row * 64 + ((((col >> 3) ^ row) & 7) << 3) + (col & 7);
}
__device__ __forceinline__ short8 ldfrag(const ushort* plane, int row, int col) {
    return *(const short8*)&plane[swz(row, col)];
}

struct AttnAllP {
    const float* Qf[3];
    const ushort* Kh[3]; const ushort* Kl[3];
    const ushort* Vth[3]; const ushort* Vtl[3];
    float* O[3];
};

__global__ __launch_bounds__(256) void attn_all(AttnAllP p)
{
    __shared__ ushort Qh_[4096], Ql_[4096];
    __shared__ ushort Kh_[4096], Kl_[4096];
    __shared__ ushort Vh_[4096], Vl_[4096];

    const int bx = blockIdx.x;
    const int seg = (bx < 20) ? 0 : (bx < 40) ? 1 : 2;
    const int q0 = (bx - ((seg == 0) ? 0 : (seg == 1) ? 20 : 40)) * 64;
    const int h = blockIdx.y;
    const int t = threadIdx.x;
    const int wave = t >> 6, lane = t & 63;
    const int quad = lane >> 4, l16 = lane & 15;
    const int wq0 = wave * 16;

    const float* Qf = p.Qf[seg];
    const ushort* Kh = p.Kh[seg]; const ushort* Kl = p.Kl[seg];
    const ushort* Vth = p.Vth[seg]; const ushort* Vtl = p.Vtl[seg];

    const int srow = t >> 2, c0 = (t & 3) << 4;
    const int g0 = c0 >> 3;
    const int p0 = ((g0 ^ (srow & 7)) & 7) << 3;
    const int p1 = (((g0 + 1) ^ (srow & 7)) & 7) << 3;

    // ---- Q staging, 0.125 softmax scale folded in (exact pow2) ----
    {
        const float* src = Qf + (size_t)(q0 + srow) * DIM + h * HD + c0;
        float x[16];
        *(float4*)&x[0]  = *(const float4*)(src);
        *(float4*)&x[4]  = *(const float4*)(src + 4);
        *(float4*)&x[8]  = *(const float4*)(src + 8);
        *(float4*)&x[12] = *(const float4*)(src + 12);
        ushort hi[16], lo[16];
#pragma unroll
        for (int i = 0; i < 16; ++i) {
            const float xs = x[i] * 0.125f;
            hi[i] = f2bf(xs);
            lo[i] = f2bf(xs - bf2f(hi[i]));
        }
        *(uint4*)&Qh_[srow * 64 + p0] = *(uint4*)&hi[0];
        *(uint4*)&Qh_[srow * 64 + p1] = *(uint4*)&hi[8];
        *(uint4*)&Ql_[srow * 64 + p0] = *(uint4*)&lo[0];
        *(uint4*)&Ql_[srow * 64 + p1] = *(uint4*)&lo[8];
    }
    // Within-wave store->read (wave stages its own 16 rows; no barrier).
    short8 qfh[2], qfl[2];
#pragma unroll
    for (int c = 0; c < 2; ++c) {
        qfh[c] = ldfrag(Qh_, wq0 + l16, c * 32 + quad * 8);
        qfl[c] = ldfrag(Ql_, wq0 + l16, c * 32 + quad * 8);
    }

    float m_[4], l_[4];
#pragma unroll
    for (int r = 0; r < 4; ++r) { m_[r] = -3e38f; l_[r] = 0.0f; }
    f32x4 Oacc[4];
#pragma unroll
    for (int j = 0; j < 4; ++j) Oacc[j] = (f32x4)(0.0f);

    for (int kv0 = 0; kv0 < SEQ; kv0 += 64) {
        __syncthreads();
        {
            const size_t off = (size_t)(kv0 + srow) * DIM + h * HD + c0;
            *(uint4*)&Kh_[srow * 64 + p0] = *(const uint4*)(Kh + off);
            *(uint4*)&Kh_[srow * 64 + p1] = *(const uint4*)(Kh + off + 8);
            *(uint4*)&Kl_[srow * 64 + p0] = *(const uint4*)(Kl + off);
            *(uint4*)&Kl_[srow * 64 + p1] = *(const uint4*)(Kl + off + 8);
        }
        {
            const size_t off = (size_t)(h * HD + srow) * SEQ + kv0 + c0;
            *(uint4*)&Vh_[srow * 64 + p0] = *(const uint4*)(Vth + off);
            *(uint4*)&Vh_[srow * 64 + p1] = *(const uint4*)(Vth + off + 8);
            *(uint4*)&Vl_[srow * 64 + p0] = *(const uint4*)(Vtl + off);
            *(uint4*)&Vl_[srow * 64 + p1] = *(const uint4*)(Vtl + off + 8);
        }
        __syncthreads();

        f32x4 S[4];
#pragma unroll
        for (int j = 0; j < 4; ++j) S[j] = (f32x4)(0.0f);
        __builtin_amdgcn_s_setprio(1);
#pragma unroll
        for (int c = 0; c < 2; ++c) {
#pragma unroll
            for (int j = 0; j < 4; ++j) {
                short8 bh = ldfrag(Kh_, j * 16 + l16, c * 32 + quad * 8);
                short8 bl = ldfrag(Kl_, j * 16 + l16, c * 32 + quad * 8);
                S[j] = __builtin_amdgcn_mfma_f32_16x16x32_bf16(qfh[c], bh, S[j], 0, 0, 0);
                S[j] = __builtin_amdgcn_mfma_f32_16x16x32_bf16(qfl[c], bh, S[j], 0, 0, 0);
                S[j] = __builtin_amdgcn_mfma_f32_16x16x32_bf16(qfh[c], bl, S[j], 0, 0, 0);
            }
        }
        __builtin_amdgcn_s_setprio(0);

        float alpha[4];
#pragma unroll
        for (int r = 0; r < 4; ++r) {
            float mx = fmaxf(fmaxf(S[0][r], S[1][r]), fmaxf(S[2][r], S[3][r]));
            mx = fmaxf(mx, __shfl_xor(mx, 1));
            mx = fmaxf(mx, __shfl_xor(mx, 2));
            mx = fmaxf(mx, __shfl_xor(mx, 4));
            mx = fmaxf(mx, __shfl_xor(mx, 8));
            float mn = fmaxf(m_[r], mx);
            alpha[r] = __expf(m_[r] - mn);
            m_[r] = mn;
            float rs = 0.0f;
#pragma unroll
            for (int j = 0; j < 4; ++j) {
                float pv = __expf(S[j][r] - mn);
                S[j][r] = pv;
                rs += pv;
            }
            rs += __shfl_xor(rs, 1);
            rs += __shfl_xor(rs, 2);
            rs += __shfl_xor(rs, 4);
            rs += __shfl_xor(rs, 8);
            l_[r] = l_[r] * alpha[r] + rs;
        }
#pragma unroll
        for (int j = 0; j < 4; ++j)
#pragma unroll
            for (int r = 0; r < 4; ++r) Oacc[j][r] *= alpha[r];

        {
            const int prow = wq0 + quad * 4;
#pragma unroll
            for (int j = 0; j < 4; ++j)
#pragma unroll
                for (int r = 0; r < 4; ++r) {
                    float pv = S[j][r];
                    ushort ph = f2bf(pv);
                    ushort pl = f2bf_rz(pv - bf2f(ph));
                    int idx = swz(prow + r, j * 16 + l16);
                    Qh_[idx] = ph;
                    Ql_[idx] = pl;
                }
        }

        __builtin_amdgcn_s_setprio(1);
#pragma unroll
        for (int c = 0; c < 2; ++c) {
            short8 pah = ldfrag(Qh_, wq0 + l16, c * 32 + quad * 8);
            short8 pal = ldfrag(Ql_, wq0 + l16, c * 32 + quad * 8);
#pragma unroll
            for (int jn = 0; jn < 4; ++jn) {
                short8 vbh = ldfrag(Vh_, jn * 16 + l16, c * 32 + quad * 8);
                short8 vbl = ldfrag(Vl_, jn * 16 + l16, c * 32 + quad * 8);
                Oacc[jn] = __builtin_amdgcn_mfma_f32_16x16x32_bf16(pah, vbh, Oacc[jn], 0, 0, 0);
                Oacc[jn] = __builtin_amdgcn_mfma_f32_16x16x32_bf16(pal, vbh, Oacc[jn], 0, 0, 0);
                Oacc[jn] = __builtin_amdgcn_mfma_f32_16x16x32_bf16(pah, vbl, Oacc[jn], 0, 0, 0);
            }
        }
        __builtin_amdgcn_s_setprio(0);
    }

    // ---- final normalize + store (no partials, no Ml) ----
    float* O = p.O[seg];
    float inv[4];
#pragma unroll
    for (int r = 0; r < 4; ++r) inv[r] = 1.0f / l_[r];
#pragma unroll
    for (int r = 0; r < 4; ++r) {
        const int rowq = q0 + wq0 + quad * 4 + r;
#pragma unroll
        for (int jn = 0; jn < 4; ++jn)
            O[(size_t)rowq * DIM + h * HD + jn * 16 + l16] = Oacc[jn][r] * inv[r];
    }
}

// ---------------------------------------------------------------------------
// Light merge: A rows (+cross X on img rows) and C rows -> bf16 hi/lo
// out-proj operand planes (2560 rows).
// ---------------------------------------------------------------------------
struct MergeP {
    const float *oA, *oC, *oX;
    ushort *Xh, *Xl;
};

__global__ __launch_bounds__(256) void merge_lite(MergeP p)
{
    const int idx = blockIdx.x * 256 + threadIdx.x;
    if (idx >= 2560 * 384) return;
    const int row = idx / 384;
    const int c4 = (idx - row * 384) << 2;
    float4 r;
    if (row < SEQ) {
        r = *(const float4*)&p.oA[(size_t)row * DIM + c4];
        if (row < IMG) {
            const float4 x = *(const float4*)&p.oX[(size_t)row * DIM + c4];
            r.x += x.x; r.y += x.y; r.z += x.z; r.w += x.w;
        }
    } else {
        r = *(const float4*)&p.oC[(size_t)(row - SEQ) * DIM + c4];
    }
    float v[4] = {r.x, r.y, r.z, r.w};
    ushort hi[4], lo[4];
#pragma unroll
    for (int j = 0; j < 4; ++j) {
        hi[j] = f2bf(v[j]);
        lo[j] = f2bf(v[j] - bf2f(hi[j]));
    }
    const size_t o = (size_t)row * DIM + c4;
    *(uint2*)(p.Xh + o) = *(uint2*)hi;
    *(uint2*)(p.Xl + o) = *(uint2*)lo;
}

// ---------------------------------------------------------------------------
extern "C" void kernel_launch(void* const* d_in, const int* in_sizes, int n_in,
                              void* d_out, int out_size, void* d_ws, size_t ws_size,
                              hipStream_t stream) {
    (void)in_sizes; (void)n_in; (void)out_size; (void)ws_size;
    const void* hs   = d_in[0];
    const void* ehs  = d_in[1];
    const void* hsc  = d_in[2];
    const void* ehsc = d_in[3];
    const void* i2q  = d_in[4];
    const void* pe   = d_in[5];
#define W_(i) ((const void*)d_in[i])

    char* base = (char*)d_ws;
    int* flag = (int*)base;
    char* ptr = base + 256;
    auto alloc = [&](size_t bytes) { char* r = ptr; ptr += bytes; return r; };
    float* q1  = (float*)alloc(SD * 4);      // C q f32 (roped inplace); later Xl
    float* k1  = (float*)alloc(SD * 4);      // C k f32; later O_X
    float* v1  = (float*)alloc(SD * 4);      // A v f32; later O_A
    float* vC  = (float*)alloc(SD * 4);      // C v f32; later O_C
    float* qA  = (float*)alloc(SD * 4);      // A q f32; later Xh
    float* qx  = (float*)alloc(IDSZ * 4);    // X q f32
    ushort* khA  = (ushort*)alloc(SD * 2);
    ushort* kloA = (ushort*)alloc(SD * 2);
    ushort* vthA = (ushort*)alloc(SD * 2);
    ushort* vtlA = (ushort*)alloc(SD * 2);
    ushort* khC  = (ushort*)alloc(SD * 2);
    ushort* kloC = (ushort*)alloc(SD * 2);
    ushort* vthC = (ushort*)alloc(SD * 2);
    ushort* vtlC = (ushort*)alloc(SD * 2);
    ushort* Wbf = (ushort*)alloc(16 * WSZ * 2);
    ushort* Xbf = (ushort*)alloc(2 * SD * 2);
    ushort* Xh = (ushort*)qA;     // dead after attn_all
    ushort* Xl = (ushort*)q1;     // dead after attn_all

    dim3 blk(256);
    detect_dtype<<<1, blk, 0, stream>>>(hs, flag);

    {
        CvtP cp;
        const int wsrc[16] = {6, 8, 10, 12, 14, 16, 22, 24, 26, 28, 30, 32,
                              18, 20, 34, 36};
        for (int j = 0; j < 16; ++j) {
            cp.src[j] = W_(wsrc[j]);
            cp.dst[j] = Wbf + (size_t)j * WSZ;
            cp.n8[j] = (int)(WSZ / 8);
        }
        cp.src[16] = hs;   cp.dst[16] = Xbf;             cp.n8[16] = (int)(IDSZ / 8);
        cp.src[17] = ehs;  cp.dst[17] = Xbf + IDSZ;      cp.n8[17] = (int)((size_t)TXT * DIM / 8);
        cp.src[18] = hsc;  cp.dst[18] = Xbf + SD;        cp.n8[18] = (int)(IDSZ / 8);
        cp.src[19] = ehsc; cp.dst[19] = Xbf + SD + IDSZ; cp.n8[19] = (int)((size_t)TXT * DIM / 8);
        convert_bf16<<<dim3((int)(WSZ / 8 + 255) / 256, 20), blk, 0, stream>>>(cp, flag);
    }

    QKV3P qp;
    qp.Xb = Xbf;
    qp.Wb = Wbf;
    {
        const int bsrc[12] = {7, 9, 11, 13, 15, 17, 23, 25, 27, 29, 31, 33};
        for (int j = 0; j < 12; ++j) qp.B[j] = W_(bsrc[j]);
    }
    for (int j = 0; j < 6; ++j) { qp.Y[j] = nullptr; qp.Yh[j] = nullptr; qp.Yl[j] = nullptr; }
    qp.Y[0] = qA;
    qp.Yh[1] = khA; qp.Yl[1] = kloA;
    qp.Y[2] = v1;
    qp.Y[3] = q1;
    qp.Y[4] = k1;
    qp.Y[5] = vC;
    gemm_qkv_v4<<<dim3(36, 20), blk, 0, stream>>>(qp, flag);

    {
        PrepP pp;
        pp.v1 = v1; pp.vC = vC;
        pp.vthA = vthA; pp.vtlA = vtlA; pp.vthC = vthC; pp.vtlC = vtlC;
        pp.q1 = q1;
        pp.k1 = k1; pp.khC = khC; pp.kloC = kloC;
        pp.i2q = i2q; pp.qx = qx;
        pp.pe = pe;
        const int ropeBlocks = (RN0 + RN1 + RN2 + 255) / 256;
        prep_fused<<<VT_BLKS + ropeBlocks, blk, 0, stream>>>(pp, flag);
    }

    {
        AttnAllP ap;
        ap.Qf[0] = qA; ap.Qf[1] = q1; ap.Qf[2] = qx;
        ap.Kh[0] = khA; ap.Kl[0] = kloA;
        ap.Kh[1] = khC; ap.Kl[1] = kloC;
        ap.Kh[2] = khC; ap.Kl[2] = kloC;
        ap.Vth[0] = vthA; ap.Vtl[0] = vtlA;
        ap.Vth[1] = vthC; ap.Vtl[1] = vtlC;
        ap.Vth[2] = vthC; ap.Vtl[2] = vtlC;
        ap.O[0] = v1;    // A v dead post-vtrans
        ap.O[1] = vC;    // C v dead post-vtrans
        ap.O[2] = k1;    // C k dead post-rope
        attn_all<<<dim3(56, NH), blk, 0, stream>>>(ap);
    }

    {
        MergeP mp;
        mp.oA = v1; mp.oC = vC; mp.oX = k1;
        mp.Xh = Xh; mp.Xl = Xl;
        merge_lite<<<(2560 * 384 + 255) / 256, blk, 0, stream>>>(mp);
    }

    {
        OutP op;
        op.Xh = Xh; op.Xl = Xl;
        op.Wb = Wbf + (size_t)12 * WSZ;
        op.B[0] = W_(19); op.B[1] = W_(21); op.B[2] = W_(35); op.B[3] = W_(37);
        op.out = d_out;
        gemm_out_v4<<<dim3(12, 40), blk, 0, stream>>>(op, flag);
    }
#undef W_
}